// Round 5
// baseline (436.244 us; speedup 1.0000x reference)
//
#include <hip/hip_runtime.h>
#include <hip/hip_bf16.h>

typedef unsigned int u32;
typedef unsigned long long u64;

#define B 8
#define NANCH 100800
#define NCH 85
#define KPRE 1024
#define MAXDET 100
#define CONF 0.25f
#define IOU_T 0.45f
#define EPS_F 1e-7f
#define MAX_WH 7680.0f
#define CAP 4096
#define NBIN 257
#define BASEBITS 0x3E800000u  // bits of 0.25f

// K1 geometry (round 5): 16 rows per chunk, 4 lanes per row (20 classes each).
// Block LDS = 4*5440 + 8224 = 29984 B -> floor(163840/29984) = 5 blocks/CU
// -> 20 waves/CU (launch_bounds(256,5), VGPR cap 102 — live set ~70, no spill).
// Grid 1260 blocks = 5040 waves: 50400/5040 = exactly 10 chunks/wave (zero
// remainder imbalance); 1260 <= 5*256 so all blocks co-resident. The last
// prefetch is guarded out (round-4 version re-read the current chunk: 22 MB
// = 8% wasted HBM traffic).
#define ROWS 16
#define RDW 85                     // dwords per row
#define CHDW (ROWS * RDW)          // 1360 dwords = 5440 B per chunk
#define CHF4 (CHDW / 4)            // 340 float4 per chunk
#define NCHUNK (B * NANCH / ROWS)  // 50400
#define CPB (NANCH / ROWS)         // 6300 chunks per batch (exact)

// ---------------- K1: score + argmax + fused per-batch histogram ----------------
// Wave stages 16 contiguous rows (5440 B) into its private LDS slice with
// coalesced float4 loads (5 full + 20-lane tail); lane scans 20 classes of
// row (lane&15) from LDS. Strict-> scan ascending c + strict-> cross-quarter
// combine keep argmax's lowest-index-wins semantics (quarters are ordered by
// class range). Software pipeline: next chunk's loads issue before the current
// chunk's ds_write+scan, so ~6 loads/wave stay in flight continuously.
// No barriers in the main loop: slice is wave-private.
__global__ __launch_bounds__(256, 5) void score_kernel(const float* __restrict__ pred,
                                                       u32* __restrict__ keys,
                                                       unsigned char* __restrict__ cls8,
                                                       u32* __restrict__ ghist) {
    __shared__ __align__(16) float sbuf[4 * CHDW];  // 21760 B: 4 wave-private slices
    __shared__ u32 lh[B * NBIN];                    // 8224 B
    for (int i = threadIdx.x; i < B * NBIN; i += 256) lh[i] = 0;
    __syncthreads();

    const int lane = threadIdx.x & 63;
    const int wloc = threadIdx.x >> 6;
    const int q    = lane >> 4;   // quarter: classes [20q, 20q+20)
    const int r    = lane & 15;   // row within chunk
    float* sw = &sbuf[wloc * CHDW];
    const int gwave = (blockIdx.x << 2) | wloc;
    const int nwaves = gridDim.x << 2;

    // prologue: load first chunk into registers
    float4 a0, a1, a2, a3, a4, at;
    a0 = a1 = a2 = a3 = a4 = at = make_float4(0.f, 0.f, 0.f, 0.f);
    if (gwave < NCHUNK) {
        const float4* s4 = (const float4*)pred + (size_t)gwave * CHF4;
        a0 = s4[0 * 64 + lane];
        a1 = s4[1 * 64 + lane];
        a2 = s4[2 * 64 + lane];
        a3 = s4[3 * 64 + lane];
        a4 = s4[4 * 64 + lane];
        if (lane < 20) at = s4[320 + lane];
    }

    for (int ch = gwave; ch < NCHUNK; ch += nwaves) {
        // --- prefetch next chunk into regs (guarded: no redundant tail loads;
        //     branch is wave-uniform) ---
        int nx = ch + nwaves;
        float4 b0, b1, b2, b3, b4, bt;
        b0 = b1 = b2 = b3 = b4 = bt = make_float4(0.f, 0.f, 0.f, 0.f);
        if (nx < NCHUNK) {
            const float4* s4n = (const float4*)pred + (size_t)nx * CHF4;
            b0 = s4n[0 * 64 + lane];
            b1 = s4n[1 * 64 + lane];
            b2 = s4n[2 * 64 + lane];
            b3 = s4n[3 * 64 + lane];
            b4 = s4n[4 * 64 + lane];
            if (lane < 20) bt = s4n[320 + lane];
        }

        // --- write current chunk to LDS (waits only on a*, loaded last iter;
        //     b* loads stay in flight) ---
        *(float4*)&sw[(0 * 64 + lane) * 4] = a0;
        *(float4*)&sw[(1 * 64 + lane) * 4] = a1;
        *(float4*)&sw[(2 * 64 + lane) * 4] = a2;
        *(float4*)&sw[(3 * 64 + lane) * 4] = a3;
        *(float4*)&sw[(4 * 64 + lane) * 4] = a4;
        if (lane < 20) *(float4*)&sw[(320 + lane) * 4] = at;

        // --- quarter-row scan from LDS ---
        const float* row = &sw[r * RDW];
        float obj = row[4];               // 4 lanes same addr -> broadcast
        const float* cp = row + 5 + 20 * q;
        float best = -1.0f;
        int bidx = 0;
        #pragma unroll
        for (int c = 0; c < 20; ++c) {
            float v = cp[c] * obj;        // exact same product as reference
            bool g = v > best;            // strict > : first max wins within quarter
            best = g ? v : best;
            bidx = g ? c : bidx;
        }
        bidx += 20 * q;

        // --- combine quarters (lane<16 holds final; strict > => tie keeps
        //     lower quarter = lower class index for the lanes that matter) ---
        float xo = __shfl_xor(best, 16);
        int io = __shfl_xor(bidx, 16);
        bool t = xo > best;
        best = t ? xo : best;
        bidx = t ? io : bidx;
        xo = __shfl_xor(best, 32);
        io = __shfl_xor(bidx, 32);
        t = xo > best;
        best = t ? xo : best;
        bidx = t ? io : bidx;

        if (lane < 16) {
            bool valid = (obj > CONF) & (best > CONF);
            u32 k = valid ? __float_as_uint(best) : 0u;
            int a = ch * ROWS + r;
            keys[a] = k;                       // 64B contiguous per wave
            cls8[a] = (unsigned char)bidx;
            if (k) {
                int b = ch / CPB;              // chunks never straddle batches
                u32 bin = (k - BASEBITS) >> 16;
                if (bin > 256) bin = 256;
                atomicAdd(&lh[b * NBIN + bin], 1u);
            }
        }

        // rotate double-buffered staging regs
        a0 = b0; a1 = b1; a2 = b2; a3 = b3; a4 = b4; at = bt;
    }
    __syncthreads();
    for (int i = threadIdx.x; i < B * NBIN; i += 256) {
        u32 v = lh[i];
        if (v) atomicAdd(&ghist[i], v);  // no-return, fire-and-forget
    }
}

// ---------------- K2: per-batch select: pivot -> filter -> sort -> boxes ->
//                     greedy register NMS -> output (unchanged) ----------------
__global__ __launch_bounds__(1024) void select_kernel(const float* __restrict__ pred,
                                                      const u32* __restrict__ keys,
                                                      const unsigned char* __restrict__ cls8,
                                                      const u32* __restrict__ ghist,
                                                      float* __restrict__ out) {
    #pragma clang fp contract(off)
    const int b = blockIdx.x;
    const int tid = threadIdx.x;

    __shared__ u64 items[CAP];       // 32 KB
    __shared__ float s_score[KPRE];  // 4 KB
    __shared__ float s_cls[KPRE];    // 4 KB
    __shared__ float4 s_box[KPRE];   // 16 KB
    __shared__ float4 s_obox[KPRE];  // 16 KB
    __shared__ float s_area[KPRE];   // 4 KB
    __shared__ u32 s_hist[NBIN];
    __shared__ int s_piv;
    __shared__ int s_cnt;
    __shared__ int s_keep[MAXDET];
    __shared__ int s_nk;

    // --- pivot ---
    if (tid < NBIN) s_hist[tid] = ghist[b * NBIN + tid];
    if (tid == 0) s_cnt = 0;
    __syncthreads();
    if (tid == 0) {
        int cum = 0, piv = 0;
        for (int t = 256; t >= 0; --t) {
            cum += (int)s_hist[t];
            if (cum >= KPRE) { piv = t; break; }
        }
        s_piv = piv;
    }
    __syncthreads();
    const int piv = s_piv;

    // --- filter this batch's keys into LDS (uint4-vectorized) ---
    const uint4* kb4 = (const uint4*)(keys + (size_t)b * NANCH);
    const int NV = NANCH / 4;  // 25200
    for (int j = tid; j < NV; j += 1024) {
        uint4 kv = kb4[j];
        u32 ks[4] = {kv.x, kv.y, kv.z, kv.w};
        #pragma unroll
        for (int e = 0; e < 4; ++e) {
            u32 k = ks[e];
            if (k) {
                u32 bin = (k - BASEBITS) >> 16;
                if (bin > 256) bin = 256;
                if ((int)bin >= piv) {
                    int p = atomicAdd(&s_cnt, 1);
                    if (p < CAP) items[p] = (((u64)(~k)) << 32) | (u32)(j * 4 + e);
                }
            }
        }
    }
    __syncthreads();
    int n = s_cnt; if (n > CAP) n = CAP;

    // dynamic sort size: next pow2 >= max(n, 1024)
    int m = KPRE;
    while (m < n) m <<= 1;
    for (int i = tid; i < m; i += 1024)
        if (i >= n) items[i] = ~0ull;
    __syncthreads();

    // --- bitonic ascending sort of m u64 keys ---
    for (int k = 2; k <= m; k <<= 1) {
        for (int j = k >> 1; j >= 1; j >>= 1) {
            for (int p = tid; p < m / 2; p += 1024) {
                int i = ((p & ~(j - 1)) << 1) | (p & (j - 1));
                int pr = i | j;
                bool up = ((i & k) == 0);
                u64 a = items[i], c = items[pr];
                if ((a > c) == up) { items[i] = c; items[pr] = a; }
            }
            __syncthreads();
        }
    }

    // --- finalize slot tid: gather pred row, build boxes ---
    if (tid < KPRE) {
        u64 it = items[tid];
        u32 invk = (u32)(it >> 32);
        if (invk != 0xFFFFFFFFu && tid < n) {
            u32 k = ~invk;
            u32 idx = (u32)it;
            float score = __uint_as_float(k);
            const float* pb = pred + ((size_t)b * NANCH + idx) * NCH;
            float cx = pb[0], cy = pb[1], w = pb[2], h = pb[3];
            float x1 = cx - w * 0.5f;
            float y1 = cy - h * 0.5f;
            float x2 = cx + w * 0.5f;
            float y2 = cy + h * 0.5f;
            float clsf = (float)cls8[(size_t)b * NANCH + idx];
            float off = clsf * MAX_WH;
            float bx1 = x1 + off, by1 = y1 + off, bx2 = x2 + off, by2 = y2 + off;
            s_score[tid] = score;
            s_cls[tid] = clsf;
            s_box[tid] = make_float4(x1, y1, x2, y2);
            s_obox[tid] = make_float4(bx1, by1, bx2, by2);
            s_area[tid] = (bx2 - bx1) * (by2 - by1);
        } else {
            s_score[tid] = -1.0f;
            s_cls[tid] = 0.0f;
            s_box[tid] = make_float4(0.f, 0.f, 0.f, 0.f);
            s_obox[tid] = make_float4(0.f, 0.f, 0.f, 0.f);
            s_area[tid] = 0.0f;
        }
    }
    __syncthreads();

    // --- greedy NMS on wave 0: kept boxes live in registers (2 slots/lane) ---
    if (tid < 64) {
        const int lane = tid;
        float4 kb0 = make_float4(0, 0, 0, 0), kb1 = kb0;
        float ka0 = 0.0f, ka1 = 0.0f;
        int kept = 0;

        float sc_n = s_score[0];
        float4 cb_n = s_obox[0];
        float ca_n = s_area[0];

        for (int i = 0; i < KPRE; ++i) {
            float sc = sc_n;
            float4 cb = cb_n;
            float ca = ca_n;
            if (i + 1 < KPRE) {           // prefetch next candidate
                sc_n = s_score[i + 1];
                cb_n = s_obox[i + 1];
                ca_n = s_area[i + 1];
            }
            if (sc <= 0.0f) break;        // sorted: rest invalid

            bool sup0 = false, sup1 = false;
            if (lane < kept) {
                float ltx = fmaxf(cb.x, kb0.x);
                float lty = fmaxf(cb.y, kb0.y);
                float rbx = fminf(cb.z, kb0.z);
                float rby = fminf(cb.w, kb0.w);
                float iw = fmaxf(rbx - ltx, 0.0f);
                float ih = fmaxf(rby - lty, 0.0f);
                float inter = iw * ih;
                float uni = ca + ka0 - inter;
                sup0 = (inter / (uni + EPS_F)) > IOU_T;
            }
            if (lane + 64 < kept) {
                float ltx = fmaxf(cb.x, kb1.x);
                float lty = fmaxf(cb.y, kb1.y);
                float rbx = fminf(cb.z, kb1.z);
                float rby = fminf(cb.w, kb1.w);
                float iw = fmaxf(rbx - ltx, 0.0f);
                float ih = fmaxf(rby - lty, 0.0f);
                float inter = iw * ih;
                float uni = ca + ka1 - inter;
                sup1 = (inter / (uni + EPS_F)) > IOU_T;
            }
            u64 bal = __ballot(sup0 || sup1);
            if (bal == 0) {
                if (lane == 0) s_keep[kept] = i;
                if (kept < 64) {
                    if (lane == kept) { kb0 = cb; ka0 = ca; }
                } else {
                    if (lane == kept - 64) { kb1 = cb; ka1 = ca; }
                }
                ++kept;
                if (kept >= MAXDET) break;
            }
        }
        if (lane == 0) s_nk = kept;
    }
    __syncthreads();
    const int nk = s_nk;

    // --- output ---
    if (tid < MAXDET) {
        float o0 = 0, o1 = 0, o2 = 0, o3 = 0, o4 = 0, o5 = 0;
        if (tid < nk) {
            int i = s_keep[tid];
            float4 bx = s_box[i];
            o0 = bx.x; o1 = bx.y; o2 = bx.z; o3 = bx.w;
            o4 = s_score[i];
            o5 = s_cls[i];
        }
        float* po = out + ((size_t)b * MAXDET + tid) * 6;
        po[0] = o0; po[1] = o1; po[2] = o2; po[3] = o3; po[4] = o4; po[5] = o5;
    }
}

extern "C" void kernel_launch(void* const* d_in, const int* in_sizes, int n_in,
                              void* d_out, int out_size, void* d_ws, size_t ws_size,
                              hipStream_t stream) {
    const float* pred = (const float*)d_in[0];
    float* out = (float*)d_out;
    char* ws = (char*)d_ws;

    // workspace layout (bytes)
    u32* keys           = (u32*)(ws + 0);                 // 806400*4 = 3225600
    unsigned char* cls8 = (unsigned char*)(ws + 3225600); // 806400 -> 4032000
    u32* ghist          = (u32*)(ws + 4032000);           // 8*257*4 = 8224 -> 4040224

    hipMemsetAsync(ghist, 0, B * NBIN * sizeof(u32), stream);
    // 1260 blocks x 256 threads; 30 KB LDS/block -> 5 blocks/CU -> 20 waves/CU;
    // 5040 waves -> exactly 10 chunks per wave (50400/5040), zero imbalance.
    score_kernel<<<1260, 256, 0, stream>>>(pred, keys, cls8, ghist);
    select_kernel<<<B, 1024, 0, stream>>>(pred, keys, cls8, ghist, out);
}

// Round 6
// 417.934 us; speedup vs baseline: 1.0438x; 1.0438x over previous
//
#include <hip/hip_runtime.h>
#include <hip/hip_bf16.h>

typedef unsigned int u32;
typedef unsigned long long u64;

#define B 8
#define NANCH 100800
#define NCH 85
#define KPRE 1024
#define MAXDET 100
#define CONF 0.25f
#define IOU_T 0.45f
#define EPS_F 1e-7f
#define MAX_WH 7680.0f
#define CAP 4096
#define NBIN 257
#define BASEBITS 0x3E800000u  // bits of 0.25f

// K1 geometry (frozen from round 5): 16 rows per chunk, 4 lanes per row.
#define ROWS 16
#define RDW 85                     // dwords per row
#define CHDW (ROWS * RDW)          // 1360 dwords = 5440 B per chunk
#define CHF4 (CHDW / 4)            // 340 float4 per chunk
#define NCHUNK (B * NANCH / ROWS)  // 50400
#define CPB (NANCH / ROWS)         // 6300 chunks per batch (exact)

// ---------------- K1: score + argmax + fused per-batch histogram ----------------
// (unchanged from round 5 — at its memory floor; three configs all neutral)
__global__ __launch_bounds__(256, 5) void score_kernel(const float* __restrict__ pred,
                                                       u32* __restrict__ keys,
                                                       unsigned char* __restrict__ cls8,
                                                       u32* __restrict__ ghist) {
    __shared__ __align__(16) float sbuf[4 * CHDW];  // 21760 B: 4 wave-private slices
    __shared__ u32 lh[B * NBIN];                    // 8224 B
    for (int i = threadIdx.x; i < B * NBIN; i += 256) lh[i] = 0;
    __syncthreads();

    const int lane = threadIdx.x & 63;
    const int wloc = threadIdx.x >> 6;
    const int q    = lane >> 4;   // quarter: classes [20q, 20q+20)
    const int r    = lane & 15;   // row within chunk
    float* sw = &sbuf[wloc * CHDW];
    const int gwave = (blockIdx.x << 2) | wloc;
    const int nwaves = gridDim.x << 2;

    // prologue: load first chunk into registers
    float4 a0, a1, a2, a3, a4, at;
    a0 = a1 = a2 = a3 = a4 = at = make_float4(0.f, 0.f, 0.f, 0.f);
    if (gwave < NCHUNK) {
        const float4* s4 = (const float4*)pred + (size_t)gwave * CHF4;
        a0 = s4[0 * 64 + lane];
        a1 = s4[1 * 64 + lane];
        a2 = s4[2 * 64 + lane];
        a3 = s4[3 * 64 + lane];
        a4 = s4[4 * 64 + lane];
        if (lane < 20) at = s4[320 + lane];
    }

    for (int ch = gwave; ch < NCHUNK; ch += nwaves) {
        // --- prefetch next chunk into regs (wave-uniform guard) ---
        int nx = ch + nwaves;
        float4 b0, b1, b2, b3, b4, bt;
        b0 = b1 = b2 = b3 = b4 = bt = make_float4(0.f, 0.f, 0.f, 0.f);
        if (nx < NCHUNK) {
            const float4* s4n = (const float4*)pred + (size_t)nx * CHF4;
            b0 = s4n[0 * 64 + lane];
            b1 = s4n[1 * 64 + lane];
            b2 = s4n[2 * 64 + lane];
            b3 = s4n[3 * 64 + lane];
            b4 = s4n[4 * 64 + lane];
            if (lane < 20) bt = s4n[320 + lane];
        }

        // --- write current chunk to LDS ---
        *(float4*)&sw[(0 * 64 + lane) * 4] = a0;
        *(float4*)&sw[(1 * 64 + lane) * 4] = a1;
        *(float4*)&sw[(2 * 64 + lane) * 4] = a2;
        *(float4*)&sw[(3 * 64 + lane) * 4] = a3;
        *(float4*)&sw[(4 * 64 + lane) * 4] = a4;
        if (lane < 20) *(float4*)&sw[(320 + lane) * 4] = at;

        // --- quarter-row scan from LDS ---
        const float* row = &sw[r * RDW];
        float obj = row[4];
        const float* cp = row + 5 + 20 * q;
        float best = -1.0f;
        int bidx = 0;
        #pragma unroll
        for (int c = 0; c < 20; ++c) {
            float v = cp[c] * obj;        // exact same product as reference
            bool g = v > best;            // strict > : first max wins within quarter
            best = g ? v : best;
            bidx = g ? c : bidx;
        }
        bidx += 20 * q;

        // --- combine quarters (strict > keeps lowest class index on ties) ---
        float xo = __shfl_xor(best, 16);
        int io = __shfl_xor(bidx, 16);
        bool t = xo > best;
        best = t ? xo : best;
        bidx = t ? io : bidx;
        xo = __shfl_xor(best, 32);
        io = __shfl_xor(bidx, 32);
        t = xo > best;
        best = t ? xo : best;
        bidx = t ? io : bidx;

        if (lane < 16) {
            bool valid = (obj > CONF) & (best > CONF);
            u32 k = valid ? __float_as_uint(best) : 0u;
            int a = ch * ROWS + r;
            keys[a] = k;
            cls8[a] = (unsigned char)bidx;
            if (k) {
                int b = ch / CPB;
                u32 bin = (k - BASEBITS) >> 16;
                if (bin > 256) bin = 256;
                atomicAdd(&lh[b * NBIN + bin], 1u);
            }
        }

        a0 = b0; a1 = b1; a2 = b2; a3 = b3; a4 = b4; at = bt;
    }
    __syncthreads();
    for (int i = threadIdx.x; i < B * NBIN; i += 256) {
        u32 v = lh[i];
        if (v) atomicAdd(&ghist[i], v);  // fire-and-forget
    }
}

// ---------------- K2a: GPU-wide parallel filter -> compacted candidate lists ----
// 32 blocks per batch scan keys[] (uint4-coalesced), collect qualifying items
// ((~k)<<32 | idx) in LDS, then ONE global atomicAdd per block reserves a range
// in gcand[b]. Arrival order nondeterministic; the full sort in K2b restores
// the exact (~key, idx) order, so output is deterministic. Pivot recomputed
// per block from ghist (1 KB, L2-hot, LDS-staged serial scan ~1k cycles).
__global__ __launch_bounds__(256) void filter_kernel(const u32* __restrict__ keys,
                                                     const u32* __restrict__ ghist,
                                                     u32* __restrict__ gcnt,
                                                     u64* __restrict__ gcand) {
    __shared__ u64 sitems[4096];    // 32 KB: worst case every scanned key matches
    __shared__ u32 s_hist[NBIN];
    __shared__ int s_piv, s_cnt, s_base;

    const int b = blockIdx.x >> 5;   // batch
    const int g = blockIdx.x & 31;   // slice within batch
    const int tid = threadIdx.x;

    for (int i = tid; i < NBIN; i += 256) s_hist[i] = ghist[b * NBIN + i];
    if (tid == 0) s_cnt = 0;
    __syncthreads();
    if (tid == 0) {
        int cum = 0, piv = 0;
        for (int t = 256; t >= 0; --t) {
            cum += (int)s_hist[t];
            if (cum >= KPRE) { piv = t; break; }
        }
        s_piv = piv;
    }
    __syncthreads();
    const int piv = s_piv;

    const uint4* kb4 = (const uint4*)(keys + (size_t)b * NANCH);
    const int NV = NANCH / 4;  // 25200
    for (int j = (g << 8) + tid; j < NV; j += 8192) {
        uint4 kv = kb4[j];
        u32 ks[4] = {kv.x, kv.y, kv.z, kv.w};
        #pragma unroll
        for (int e = 0; e < 4; ++e) {
            u32 k = ks[e];
            if (k) {
                u32 bin = (k - BASEBITS) >> 16;
                if (bin > 256) bin = 256;
                if ((int)bin >= piv) {
                    int p = atomicAdd(&s_cnt, 1);
                    if (p < 4096) sitems[p] = (((u64)(~k)) << 32) | (u32)(j * 4 + e);
                }
            }
        }
    }
    __syncthreads();
    int cnt = s_cnt; if (cnt > 4096) cnt = 4096;
    if (tid == 0) s_base = (int)atomicAdd(&gcnt[b], (u32)cnt);
    __syncthreads();
    const int base = s_base;
    u64* gout = gcand + (size_t)b * CAP;
    for (int i = tid; i < cnt; i += 256) {
        int pos = base + i;
        if (pos < CAP) gout[pos] = sitems[i];
    }
}

// ---------------- K2b: per-batch sort -> boxes -> greedy register NMS -> output --
__global__ __launch_bounds__(1024) void selnms_kernel(const float* __restrict__ pred,
                                                      const unsigned char* __restrict__ cls8,
                                                      const u32* __restrict__ gcnt,
                                                      const u64* __restrict__ gcand,
                                                      float* __restrict__ out) {
    #pragma clang fp contract(off)
    const int b = blockIdx.x;
    const int tid = threadIdx.x;

    __shared__ u64 items[CAP];       // 32 KB
    __shared__ float s_score[KPRE];  // 4 KB
    __shared__ float s_cls[KPRE];    // 4 KB
    __shared__ float4 s_box[KPRE];   // 16 KB
    __shared__ float4 s_obox[KPRE];  // 16 KB
    __shared__ float s_area[KPRE];   // 4 KB
    __shared__ int s_keep[MAXDET];
    __shared__ int s_nk;

    // --- load compacted candidates (coalesced, ~14 KB) ---
    int nq = (int)gcnt[b];
    int n = nq > CAP ? CAP : nq;
    const u64* gin = gcand + (size_t)b * CAP;
    for (int i = tid; i < n; i += 1024) items[i] = gin[i];

    // dynamic sort size: next pow2 >= max(n, 1024)
    int m = KPRE;
    while (m < n) m <<= 1;
    for (int i = tid; i < m; i += 1024)
        if (i >= n) items[i] = ~0ull;
    __syncthreads();

    // --- bitonic ascending sort of m u64 keys ---
    for (int k = 2; k <= m; k <<= 1) {
        for (int j = k >> 1; j >= 1; j >>= 1) {
            for (int p = tid; p < m / 2; p += 1024) {
                int i = ((p & ~(j - 1)) << 1) | (p & (j - 1));
                int pr = i | j;
                bool up = ((i & k) == 0);
                u64 a = items[i], c = items[pr];
                if ((a > c) == up) { items[i] = c; items[pr] = a; }
            }
            __syncthreads();
        }
    }

    // --- finalize slot tid: gather pred row, build boxes ---
    if (tid < KPRE) {
        u64 it = items[tid];
        u32 invk = (u32)(it >> 32);
        if (invk != 0xFFFFFFFFu && tid < n) {
            u32 k = ~invk;
            u32 idx = (u32)it;
            float score = __uint_as_float(k);
            const float* pb = pred + ((size_t)b * NANCH + idx) * NCH;
            float cx = pb[0], cy = pb[1], w = pb[2], h = pb[3];
            float x1 = cx - w * 0.5f;
            float y1 = cy - h * 0.5f;
            float x2 = cx + w * 0.5f;
            float y2 = cy + h * 0.5f;
            float clsf = (float)cls8[(size_t)b * NANCH + idx];
            float off = clsf * MAX_WH;
            float bx1 = x1 + off, by1 = y1 + off, bx2 = x2 + off, by2 = y2 + off;
            s_score[tid] = score;
            s_cls[tid] = clsf;
            s_box[tid] = make_float4(x1, y1, x2, y2);
            s_obox[tid] = make_float4(bx1, by1, bx2, by2);
            s_area[tid] = (bx2 - bx1) * (by2 - by1);
        } else {
            s_score[tid] = -1.0f;
            s_cls[tid] = 0.0f;
            s_box[tid] = make_float4(0.f, 0.f, 0.f, 0.f);
            s_obox[tid] = make_float4(0.f, 0.f, 0.f, 0.f);
            s_area[tid] = 0.0f;
        }
    }
    __syncthreads();

    // --- greedy NMS on wave 0: kept boxes live in registers (2 slots/lane) ---
    if (tid < 64) {
        const int lane = tid;
        float4 kb0 = make_float4(0, 0, 0, 0), kb1 = kb0;
        float ka0 = 0.0f, ka1 = 0.0f;
        int kept = 0;

        float sc_n = s_score[0];
        float4 cb_n = s_obox[0];
        float ca_n = s_area[0];

        for (int i = 0; i < KPRE; ++i) {
            float sc = sc_n;
            float4 cb = cb_n;
            float ca = ca_n;
            if (i + 1 < KPRE) {           // prefetch next candidate
                sc_n = s_score[i + 1];
                cb_n = s_obox[i + 1];
                ca_n = s_area[i + 1];
            }
            if (sc <= 0.0f) break;        // sorted: rest invalid

            bool sup0 = false, sup1 = false;
            if (lane < kept) {
                float ltx = fmaxf(cb.x, kb0.x);
                float lty = fmaxf(cb.y, kb0.y);
                float rbx = fminf(cb.z, kb0.z);
                float rby = fminf(cb.w, kb0.w);
                float iw = fmaxf(rbx - ltx, 0.0f);
                float ih = fmaxf(rby - lty, 0.0f);
                float inter = iw * ih;
                float uni = ca + ka0 - inter;
                sup0 = (inter / (uni + EPS_F)) > IOU_T;
            }
            if (lane + 64 < kept) {
                float ltx = fmaxf(cb.x, kb1.x);
                float lty = fmaxf(cb.y, kb1.y);
                float rbx = fminf(cb.z, kb1.z);
                float rby = fminf(cb.w, kb1.w);
                float iw = fmaxf(rbx - ltx, 0.0f);
                float ih = fmaxf(rby - lty, 0.0f);
                float inter = iw * ih;
                float uni = ca + ka1 - inter;
                sup1 = (inter / (uni + EPS_F)) > IOU_T;
            }
            u64 bal = __ballot(sup0 || sup1);
            if (bal == 0) {
                if (lane == 0) s_keep[kept] = i;
                if (kept < 64) {
                    if (lane == kept) { kb0 = cb; ka0 = ca; }
                } else {
                    if (lane == kept - 64) { kb1 = cb; ka1 = ca; }
                }
                ++kept;
                if (kept >= MAXDET) break;
            }
        }
        if (lane == 0) s_nk = kept;
    }
    __syncthreads();
    const int nk = s_nk;

    // --- output ---
    if (tid < MAXDET) {
        float o0 = 0, o1 = 0, o2 = 0, o3 = 0, o4 = 0, o5 = 0;
        if (tid < nk) {
            int i = s_keep[tid];
            float4 bx = s_box[i];
            o0 = bx.x; o1 = bx.y; o2 = bx.z; o3 = bx.w;
            o4 = s_score[i];
            o5 = s_cls[i];
        }
        float* po = out + ((size_t)b * MAXDET + tid) * 6;
        po[0] = o0; po[1] = o1; po[2] = o2; po[3] = o3; po[4] = o4; po[5] = o5;
    }
}

extern "C" void kernel_launch(void* const* d_in, const int* in_sizes, int n_in,
                              void* d_out, int out_size, void* d_ws, size_t ws_size,
                              hipStream_t stream) {
    const float* pred = (const float*)d_in[0];
    float* out = (float*)d_out;
    char* ws = (char*)d_ws;

    // workspace layout (bytes)
    u32* keys           = (u32*)(ws + 0);                 // 806400*4 = 3225600
    unsigned char* cls8 = (unsigned char*)(ws + 3225600); // 806400 -> 4032000
    u32* ghist          = (u32*)(ws + 4032000);           // 8*257*4 = 8224 -> 4040224
    u32* gcnt           = (u32*)(ws + 4040224);           // 8*4 = 32   -> 4040256
    u64* gcand          = (u64*)(ws + 4040256);           // 8*4096*8 = 262144 -> 4302400

    // one memset covers ghist + gcnt (contiguous)
    hipMemsetAsync(ghist, 0, B * NBIN * sizeof(u32) + B * sizeof(u32), stream);
    // 1260 blocks x 256 threads; 30 KB LDS/block -> 5 blocks/CU -> 20 waves/CU.
    score_kernel<<<1260, 256, 0, stream>>>(pred, keys, cls8, ghist);
    // GPU-wide filter: 32 blocks/batch.
    filter_kernel<<<256, 256, 0, stream>>>(keys, ghist, gcnt, gcand);
    // per-batch sort + NMS + output.
    selnms_kernel<<<B, 1024, 0, stream>>>(pred, cls8, gcnt, gcand, out);
}